// Round 5
// baseline (5802.785 us; speedup 1.0000x reference)
//
#include <hip/hip_runtime.h>

// LSTM T=128,B=64,I=H=1024,L=8 — TIME-BLOCKED diagonal schedule (TB=8).
// R5: 23 launches of block-diagonals over (tb, l). Each stage (tb,l) iterates 8
// timesteps in-kernel; weights hit L2 after the first step (L3 weight traffic
// 17.3 GB -> 2.2 GB). Cross-WG per-stage barrier: release-scope atomicAdd
// (writeback, no invalidate) + relaxed polling; data freshness via 16-deep hA
// timestep ring (address uniqueness within a launch). c-state in registers.
//
// ws layout: packedW bf16 [L][256 ntile][64 kc][64 lane][8]      134,217,728 B
//            xA     bf16 [T][32 kc][4 mt][64 lane][8]             16,777,216 B
//            bias   f32  [L][4096]                                   131,072 B
//            c_state f32 [L][B][H]                                  2,097,152 B
//            hA     bf16 [16 slot][L][32 kc][4 mt][64 lane][8]    16,777,216 B
//            bar    u32  [8][64]                                       2,048 B
// total ~170 MB.

typedef __attribute__((ext_vector_type(8))) short short8;
typedef __attribute__((ext_vector_type(4))) float f32x4;

#define T_ 128
#define B_ 64
#define H_ 1024
#define L_ 8
#define TB 8
#define SLAB 65536   // shorts per [B,H] A-frag slab (32*4*64*8)

__device__ __forceinline__ unsigned short f2bf(float f) {
    unsigned u = __builtin_bit_cast(unsigned, f);
    u += 0x7fff + ((u >> 16) & 1);          // round-to-nearest-even
    return (unsigned short)(u >> 16);
}

__global__ void pack_weights(const float* __restrict__ Wih, const float* __restrict__ Whh,
                             unsigned short* __restrict__ packedW) {
    int tid = blockIdx.x * 256 + threadIdx.x;          // 8,388,608 threads
    int lane = tid & 63;
    int kchunk = (tid >> 6) & 63;
    int ntile = (tid >> 12) & 255;
    int l = tid >> 20;
    int n = ntile * 16 + (lane & 15);
    int g = n >> 10;
    int h = n & 1023;
    int kbase = kchunk * 32 + ((lane >> 4) << 3);
    short8 v;
#pragma unroll
    for (int j = 0; j < 8; ++j) {
        int k = kbase + j;
        float w = (k < 1024) ? Wih[(((l * 4 + g) * 1024 + k) << 10) + h]
                             : Whh[(((l * 4 + g) * 1024 + (k - 1024)) << 10) + h];
        v[j] = (short)f2bf(w);
    }
    *(short8*)(packedW + (size_t)tid * 8) = v;
}

// xA pack + bias + zero c_state/hA/barriers. 1,048,576 threads.
__global__ void prep_misc(const float* __restrict__ x, const float* __restrict__ bih,
                          const float* __restrict__ bhh, unsigned short* __restrict__ xA,
                          float* __restrict__ bias, float* __restrict__ c_state,
                          unsigned short* __restrict__ hA, unsigned* __restrict__ bar) {
    int tid = blockIdx.x * 256 + threadIdx.x;
    int ioct = tid & 127;
    int b = (tid >> 7) & 63;
    int t = tid >> 13;
    int i0 = ioct * 8;
    const float* src = x + ((size_t)(t * 64 + b) << 10) + i0;
    short8 v;
#pragma unroll
    for (int j = 0; j < 8; ++j) v[j] = (short)f2bf(src[j]);
    int kc = i0 >> 5;
    int q = (i0 >> 3) & 3;
    int mt = b >> 4;
    int m = b & 15;
    *(short8*)(xA + (size_t)t * SLAB + (((kc * 4 + mt) * 64 + q * 16 + m) << 3)) = v;

    if (tid < L_ * 4096) bias[tid] = bih[tid] + bhh[tid];
    if (tid < L_ * B_ * H_ / 2) { c_state[2 * tid] = 0.f; c_state[2 * tid + 1] = 0.f; }
    *(short8*)(hA + (size_t)tid * 8) = (short8)0;      // 16 slots * 8 layers * SLAB
    if (tid < 8) bar[tid * 64] = 0u;
}

// Block-diagonal D: stage l = lmin + blockIdx.y, tb = D - l, timesteps tb*8..tb*8+7.
// blockIdx.x in [0,64): 16-unit strip. wave = K-quarter; each wave does all 4 gates.
__global__ __launch_bounds__(256, 2)
void lstm_diag(const unsigned short* __restrict__ packedW,
               const unsigned short* __restrict__ xA,
               const float* __restrict__ bias,
               float* __restrict__ c_state,
               unsigned short* __restrict__ hA,
               unsigned* __restrict__ bar,
               float* __restrict__ out,
               int D, int lmin) {
    __shared__ float P[4 * 4 * 16 * 68];    // [w][g][u][b pad68] = 69,632 B (2 WG/CU)
    const int l = lmin + blockIdx.y;
    const int tb = D - l;
    const int strip = blockIdx.x;
    const int tid = threadIdx.x;
    const int lane = tid & 63;
    const int kq = tid >> 6;                // split-K quarter
    const int m = lane & 15;
    const int q = lane >> 4;

    const int kc0 = (kq & 1) * 16;
    const unsigned short* Bp0 = packedW + (((size_t)l * 256 + 0 * 64 + strip) * 32768)
                              + (size_t)(kq * 16) * 512 + lane * 8;
    const unsigned short* Bp1 = Bp0 + (size_t)64 * 32768;
    const unsigned short* Bp2 = Bp0 + (size_t)128 * 32768;
    const unsigned short* Bp3 = Bp0 + (size_t)192 * 32768;

    // epilogue identity + register-resident c
    const int u = tid & 15;
    const int b0i = (tid >> 4) << 2;
    const int ug = strip * 16 + u;
    const float* bs = bias + l * 4096;
    const float bi = bs[ug], bff = bs[1024 + ug], bc = bs[2048 + ug], bo = bs[3072 + ug];
    float creg[4];
#pragma unroll
    for (int rb = 0; rb < 4; ++rb)
        creg[rb] = c_state[((l * 64 + b0i + rb) << 10) + ug];
    const int hbase = ((ug >> 5) * 4) * 64 * 8 + (((ug >> 3) & 3) * 16) * 8 + (ug & 7);
    unsigned* barl = bar + l * 64;

    for (int i = 0; i < TB; ++i) {
        const int t = tb * TB + i;
        const unsigned short* slab0 = (l == 0)
            ? (xA + (size_t)t * SLAB)
            : (hA + (size_t)((t & 15) * L_ + (l - 1)) * SLAB);
        const unsigned short* slab1 = hA + (size_t)((((t + 15) & 15)) * L_ + l) * SLAB;
        const unsigned short* A = (kq < 2) ? slab0 : slab1;

        f32x4 acc[4][4];                    // [gate][mt]
#pragma unroll
        for (int g = 0; g < 4; ++g)
#pragma unroll
            for (int mt = 0; mt < 4; ++mt) acc[g][mt] = (f32x4)0.f;

#pragma unroll 2
        for (int kc = 0; kc < 16; ++kc) {
            short8 a[4];
#pragma unroll
            for (int mt = 0; mt < 4; ++mt)
                a[mt] = *(const short8*)(A + (((kc0 + kc) * 4 + mt) * 64 + lane) * 8);
            short8 b0 = *(const short8*)(Bp0 + kc * 512);
            short8 b1 = *(const short8*)(Bp1 + kc * 512);
            short8 b2 = *(const short8*)(Bp2 + kc * 512);
            short8 b3 = *(const short8*)(Bp3 + kc * 512);
#pragma unroll
            for (int mt = 0; mt < 4; ++mt) {
                acc[0][mt] = __builtin_amdgcn_mfma_f32_16x16x32_bf16(a[mt], b0, acc[0][mt], 0, 0, 0);
                acc[1][mt] = __builtin_amdgcn_mfma_f32_16x16x32_bf16(a[mt], b1, acc[1][mt], 0, 0, 0);
                acc[2][mt] = __builtin_amdgcn_mfma_f32_16x16x32_bf16(a[mt], b2, acc[2][mt], 0, 0, 0);
                acc[3][mt] = __builtin_amdgcn_mfma_f32_16x16x32_bf16(a[mt], b3, acc[3][mt], 0, 0, 0);
            }
        }

#pragma unroll
        for (int g = 0; g < 4; ++g)
#pragma unroll
            for (int mt = 0; mt < 4; ++mt)
                *(f32x4*)&P[((kq * 4 + g) * 16 + m) * 68 + mt * 16 + q * 4] = acc[g][mt];
        __syncthreads();

        // epilogue: reduce 4 K-partials, activations, c/h update (c in registers)
        {
            f32x4 G[4];
#pragma unroll
            for (int g = 0; g < 4; ++g) G[g] = (f32x4)0.f;
#pragma unroll
            for (int w = 0; w < 4; ++w)
#pragma unroll
                for (int g = 0; g < 4; ++g)
                    G[g] += *(const f32x4*)&P[((w * 4 + g) * 16 + u) * 68 + b0i];
            unsigned short* hslab = hA + (size_t)((t & 15) * L_ + l) * SLAB;
#pragma unroll
            for (int rb = 0; rb < 4; ++rb) {
                int b = b0i + rb;
                float gi = G[0][rb] + bi;
                float gf = G[1][rb] + bff;
                float gc = G[2][rb] + bc;
                float go = G[3][rb] + bo;
                float ig = 1.f / (1.f + __expf(-gi));
                float fg = 1.f / (1.f + __expf(-gf));
                float cg = tanhf(gc);
                float og = 1.f / (1.f + __expf(-go));
                float cnew = fg * creg[rb] + ig * cg;
                creg[rb] = cnew;
                float hnew = og * tanhf(cnew);
                hslab[hbase + ((b >> 4) * 64 + (b & 15)) * 8] = f2bf(hnew);
                if (l == 7 && t == 127) out[(b << 10) + ug] = hnew;
            }
        }

        if (i < TB - 1) {
            __syncthreads();                // all 256 threads' h stores drained (vmcnt0 before barrier)
            if (tid == 0) {
                // release RMW: waitcnt + L2 writeback (no invalidate -> weights stay L2-warm)
                __hip_atomic_fetch_add(barl, 1u, __ATOMIC_RELEASE, __HIP_MEMORY_SCOPE_AGENT);
                unsigned tgt = 64u * (7 * tb + i + 1);
                unsigned spin = 0;
                while (__hip_atomic_load(barl, __ATOMIC_RELAXED, __HIP_MEMORY_SCOPE_AGENT) < tgt
                       && ++spin < (1u << 24))
                    __builtin_amdgcn_s_sleep(2);
            }
            __syncthreads();                // data loads of next step can't start before this
        }
    }

#pragma unroll
    for (int rb = 0; rb < 4; ++rb)
        c_state[((l * 64 + b0i + rb) << 10) + ug] = creg[rb];
}

extern "C" void kernel_launch(void* const* d_in, const int* in_sizes, int n_in,
                              void* d_out, int out_size, void* d_ws, size_t ws_size,
                              hipStream_t stream) {
    const float* x   = (const float*)d_in[0];
    const float* Wih = (const float*)d_in[1];
    const float* Whh = (const float*)d_in[2];
    const float* bih = (const float*)d_in[3];
    const float* bhh = (const float*)d_in[4];
    float* out = (float*)d_out;

    char* ws = (char*)d_ws;
    unsigned short* packedW = (unsigned short*)ws;
    unsigned short* xA      = (unsigned short*)(ws + 134217728);
    float* bias             = (float*)(ws + 150994944);
    float* c_state          = (float*)(ws + 151126016);
    unsigned short* hA      = (unsigned short*)(ws + 153223168);
    unsigned* bar           = (unsigned*)(ws + 170000384);

    hipLaunchKernelGGL(pack_weights, dim3(32768), dim3(256), 0, stream, Wih, Whh, packedW);
    hipLaunchKernelGGL(prep_misc, dim3(4096), dim3(256), 0, stream,
                       x, bih, bhh, xA, bias, c_state, hA, bar);
    for (int D = 0; D <= 22; ++D) {
        int lmin = D > 15 ? D - 15 : 0;
        int lmax = D < 7 ? D : 7;
        hipLaunchKernelGGL(lstm_diag, dim3(64, lmax - lmin + 1), dim3(256), 0, stream,
                           packedW, xA, bias, c_state, hA, bar, out, D, lmin);
    }
}